// Round 4
// baseline (153.560 us; speedup 1.0000x reference)
//
#include <hip/hip_runtime.h>
#include <stdint.h>
#include <stddef.h>

#define NB 4
#define NL 2048
#define MODEL 512
#define NH 8
#define HD 64

// Q pre-scale: (1/sqrt(64)) * log2(e) -> scores in log2 domain
#define QSCALE 0.18033688011112042f

typedef __attribute__((ext_vector_type(8))) short short8;
typedef __attribute__((ext_vector_type(8))) __bf16 bf16x8;
typedef __attribute__((ext_vector_type(4))) float f32x4;
typedef __attribute__((ext_vector_type(16))) float f32x16;
typedef __attribute__((ext_vector_type(2))) unsigned int u32x2;

// round-to-nearest-even fp32 -> bf16 (bit pattern)
static __device__ __forceinline__ unsigned short f2bf(float x) {
  union { float f; unsigned u; } v; v.f = x;
  unsigned r = v.u + 0x7FFFu + ((v.u >> 16) & 1u);
  return (unsigned short)(r >> 16);
}

// packed fp32x2 -> bf16x2 (single HW instruction)
static __device__ __forceinline__ unsigned cvtpk(float lo, float hi) {
  unsigned r;
  asm("v_cvt_pk_bf16_f32 %0, %1, %2" : "=v"(r) : "v"(lo), "v"(hi));
  return r;
}

static __device__ __forceinline__ f32x4 mfma16(short8 a, short8 b, f32x4 c) {
  return __builtin_amdgcn_mfma_f32_16x16x32_bf16(
      __builtin_bit_cast(bf16x8, a), __builtin_bit_cast(bf16x8, b), c, 0, 0, 0);
}

static __device__ __forceinline__ f32x16 mfma32(short8 a, short8 b, f32x16 c) {
  return __builtin_amdgcn_mfma_f32_32x32x16_bf16(
      __builtin_bit_cast(bf16x8, a), __builtin_bit_cast(bf16x8, b), c, 0, 0, 0);
}

// ---------------------------------------------------------------------------
// Merged Q/K/V projection: grid 768 = 3 x 256, 256 thr (4 waves 2x2).
// C[m][n] = A[m][k] * W[n][k]; which 0: Q bf16 (scaled), 1: K bf16,
// 2: V transposed Vt[b][n][s].
// ---------------------------------------------------------------------------
__global__ __launch_bounds__(256) void qkv512(const float* __restrict__ Aq,
                                              const float* __restrict__ Ak,
                                              const float* __restrict__ Av,
                                              const float* __restrict__ Wqp,
                                              const float* __restrict__ Wkp,
                                              const float* __restrict__ Wvp,
                                              unsigned short* __restrict__ Qo,
                                              unsigned short* __restrict__ Ko,
                                              unsigned short* __restrict__ Vto) {
  __shared__ unsigned short Alds[128][72];
  __shared__ unsigned short Wlds[128][72];

  const int which = blockIdx.x >> 8;
  const int bid = blockIdx.x & 255;
  const float* A = which == 0 ? Aq : which == 1 ? Ak : Av;
  const float* W = which == 0 ? Wqp : which == 1 ? Wkp : Wvp;

  const int tid = threadIdx.x;
  const int bn = bid & 3;
  const int bm = bid >> 2;
  const int mbase = bm * 128, nbase = bn * 128;
  const int wid = tid >> 6, lane = tid & 63;
  const int lo = lane & 15, grp = lane >> 4;
  const int wm = wid >> 1, wn = wid & 1;

  f32x4 acc[4][4] = {};

#pragma unroll 1
  for (int kb = 0; kb < 8; ++kb) {
#pragma unroll
    for (int it = 0; it < 8; ++it) {
      int id = tid + it * 256;
      int row = id >> 4, cg = id & 15;
      float4 v = *(const float4*)(A + (size_t)(mbase + row) * 512 + kb * 64 + cg * 4);
      uint2 w; w.x = cvtpk(v.x, v.y); w.y = cvtpk(v.z, v.w);
      *(uint2*)&Alds[row][cg * 4] = w;
    }
#pragma unroll
    for (int it = 0; it < 8; ++it) {
      int id = tid + it * 256;
      int row = id >> 4, cg = id & 15;
      float4 v = *(const float4*)(W + (size_t)(nbase + row) * 512 + kb * 64 + cg * 4);
      uint2 w; w.x = cvtpk(v.x, v.y); w.y = cvtpk(v.z, v.w);
      *(uint2*)&Wlds[row][cg * 4] = w;
    }
    __syncthreads();

#pragma unroll
    for (int kk = 0; kk < 2; ++kk) {
      short8 aw[4], ba[4];
#pragma unroll
      for (int f = 0; f < 4; ++f)
        aw[f] = *(const short8*)&Wlds[wn * 64 + f * 16 + lo][kk * 32 + grp * 8];
#pragma unroll
      for (int f = 0; f < 4; ++f)
        ba[f] = *(const short8*)&Alds[wm * 64 + f * 16 + lo][kk * 32 + grp * 8];
#pragma unroll
      for (int mf = 0; mf < 4; ++mf)
#pragma unroll
        for (int nf = 0; nf < 4; ++nf)
          acc[mf][nf] = mfma16(aw[nf], ba[mf], acc[mf][nf]);
    }
    __syncthreads();
  }

  const float scale = (which == 0) ? QSCALE : 1.0f;
#pragma unroll
  for (int mf = 0; mf < 4; ++mf)
#pragma unroll
    for (int nf = 0; nf < 4; ++nf) {
      int m = mbase + wm * 64 + mf * 16 + lo;
      int n0 = nbase + wn * 64 + nf * 16 + grp * 4;
      f32x4 a = acc[mf][nf];
      if (which < 2) {
        unsigned short* C = which == 0 ? Qo : Ko;
        uint2 w;
        w.x = cvtpk(a[0] * scale, a[1] * scale);
        w.y = cvtpk(a[2] * scale, a[3] * scale);
        *(uint2*)(C + (size_t)m * 512 + n0) = w;
      } else {
        int b = m >> 11, s = m & 2047;
#pragma unroll
        for (int i = 0; i < 4; ++i)
          Vto[((size_t)b * 512 + n0 + i) * 2048 + s] = f2bf(a[i]);
      }
    }
}

// ---------------------------------------------------------------------------
// Output projection (bf16 A, fp32 out). 128x64 tiles, grid 512 (2 blocks/CU).
// ---------------------------------------------------------------------------
__global__ __launch_bounds__(256) void gemmWo(const unsigned short* __restrict__ A,
                                              const float* __restrict__ W,
                                              float* __restrict__ C) {
  __shared__ unsigned short Alds[128][72];
  __shared__ unsigned short Wlds[64][72];

  const int tid = threadIdx.x;
  const int bn = blockIdx.x & 7;     // 8 n-tiles of 64
  const int bm = blockIdx.x >> 3;    // 64 m-tiles of 128
  const int mbase = bm * 128, nbase = bn * 64;
  const int wid = tid >> 6, lane = tid & 63;
  const int lo = lane & 15, grp = lane >> 4;
  const int wm = wid >> 1, wn = wid & 1;   // wave tile 64m x 32n

  f32x4 acc[4][2] = {};

#pragma unroll 1
  for (int kb = 0; kb < 8; ++kb) {
#pragma unroll
    for (int it = 0; it < 4; ++it) {
      int id = tid + it * 256;
      int row = id >> 3, cg = id & 7;
      uint4 v = *(const uint4*)(A + (size_t)(mbase + row) * 512 + kb * 64 + cg * 8);
      *(uint4*)&Alds[row][cg * 8] = v;
    }
#pragma unroll
    for (int it = 0; it < 4; ++it) {
      int id = tid + it * 256;
      int row = id >> 4, cg = id & 15;
      float4 v = *(const float4*)(W + (size_t)(nbase + row) * 512 + kb * 64 + cg * 4);
      uint2 w; w.x = cvtpk(v.x, v.y); w.y = cvtpk(v.z, v.w);
      *(uint2*)&Wlds[row][cg * 4] = w;
    }
    __syncthreads();

#pragma unroll
    for (int kk = 0; kk < 2; ++kk) {
      short8 aw[2], ba[4];
#pragma unroll
      for (int f = 0; f < 2; ++f)
        aw[f] = *(const short8*)&Wlds[wn * 32 + f * 16 + lo][kk * 32 + grp * 8];
#pragma unroll
      for (int f = 0; f < 4; ++f)
        ba[f] = *(const short8*)&Alds[wm * 64 + f * 16 + lo][kk * 32 + grp * 8];
#pragma unroll
      for (int mf = 0; mf < 4; ++mf)
#pragma unroll
        for (int nf = 0; nf < 2; ++nf)
          acc[mf][nf] = mfma16(aw[nf], ba[mf], acc[mf][nf]);
    }
    __syncthreads();
  }

#pragma unroll
  for (int mf = 0; mf < 4; ++mf)
#pragma unroll
    for (int nf = 0; nf < 2; ++nf) {
      int m = mbase + wm * 64 + mf * 16 + lo;
      int n0 = nbase + wn * 32 + nf * 16 + grp * 4;
      f32x4 a = acc[mf][nf];
      float4 o;
      o.x = a[0]; o.y = a[1]; o.z = a[2]; o.w = a[3];
      *(float4*)(C + (size_t)m * 512 + n0) = o;
    }
}

// ---------------------------------------------------------------------------
// Flash attention v4: 32x32x16 MFMA, in-register P, K-only LDS (XOR-swizzled,
// b128 reads), V direct from global (issued at tile top, consumed after
// softmax), l via ones-MFMA, defer-max, XCD chunk swizzle.
// 4 waves x 32 q = 128 q/block; grid 512.
// ---------------------------------------------------------------------------
__global__ __launch_bounds__(256, 2) void attn32(const unsigned short* __restrict__ Qg,
                                                 const unsigned short* __restrict__ Kg,
                                                 const unsigned short* __restrict__ Vt,
                                                 unsigned short* __restrict__ Og) {
  __shared__ char Klds[2][8192];   // [buf][64 rows x 128B], XOR-swizzled

  const int tid = threadIdx.x;
  const int wid = tid >> 6, lane = tid & 63;
  const int ln31 = lane & 31, hl = lane >> 5;

  // XCD chunk swizzle: XCD x gets logical blocks [x*64, x*64+64) = 4 bh groups
  const int lb = ((blockIdx.x & 7) << 6) + (blockIdx.x >> 3);
  const int bh = lb >> 4, qb = lb & 15;
  const int b = bh >> 3, h = bh & 7;

  const unsigned short* Kbh = Kg + (size_t)b * 2048 * 512 + h * 64;
  const unsigned short* Vbh = Vt + ((size_t)b * 512 + h * 64) * 2048;
  const int q = qb * 128 + wid * 32 + ln31;     // this lane's q-column

  // Q B-fragments: col=q, k(d) = ks*16 + hl*8 + j
  short8 qf[4];
#pragma unroll
  for (int ks = 0; ks < 4; ++ks)
    qf[ks] = *(const short8*)(Qg + ((size_t)b * 2048 + q) * 512 + h * 64 + ks * 16 + hl * 8);

  // K staging: wave stages rows wid*16 .. wid*16+15, 8 x 16B chunks per row
  const int sr = lane >> 3, sc = lane & 7;
  const int wr0 = wid * 16 + sr, wr1 = wr0 + 8;
  const int wb0 = wr0 * 128 + ((sc * 16) ^ ((wr0 & 7) << 4));
  const int wb1 = wr1 * 128 + ((sc * 16) ^ ((wr1 & 7) << 4));
  const unsigned short* kg0 = Kbh + (size_t)wr0 * 512 + sc * 8;
  const unsigned short* kg1 = Kbh + (size_t)wr1 * 512 + sc * 8;

  // K read addressing (swizzled b128)
  const int rb0 = ln31 * 128, rb1 = (32 + ln31) * 128;
  const int sw0 = (ln31 & 7) << 4;
  const int hl16 = hl * 16;

  // V direct-load lane pointers
  const unsigned short* vp0 = Vbh + (size_t)ln31 * 2048 + hl * 8;
  const unsigned short* vp1 = vp0 + (size_t)32 * 2048;

  float mrun = -1e30f;
  f32x16 o0 = {}, o1 = {}, lacc = {};
  const short8 ones = {0x3F80, 0x3F80, 0x3F80, 0x3F80, 0x3F80, 0x3F80, 0x3F80, 0x3F80};

  // prologue: stage K tile 0
  *(uint4*)(Klds[0] + wb0) = *(const uint4*)kg0;
  *(uint4*)(Klds[0] + wb1) = *(const uint4*)kg1;
  __syncthreads();

  int cur = 0;
#pragma unroll 1
  for (int st = 0; st < 32; ++st) {
    // V loads for THIS tile (consumed after softmax) + K loads for NEXT tile
    uint4 vv0[4], vv1[4];
#pragma unroll
    for (int ks = 0; ks < 4; ++ks) {
      vv0[ks] = *(const uint4*)(vp0 + st * 64 + ks * 16);
      vv1[ks] = *(const uint4*)(vp1 + st * 64 + ks * 16);
    }
    uint4 gk0, gk1;
    if (st < 31) {
      gk0 = *(const uint4*)(kg0 + (size_t)(st + 1) * 64 * 512);
      gk1 = *(const uint4*)(kg1 + (size_t)(st + 1) * 64 * 512);
    }

    // ---- QK^T: D[s][q], two 32-row s-blocks ----
    f32x16 s0 = {}, s1 = {};
    __builtin_amdgcn_s_setprio(1);
#pragma unroll
    for (int ks = 0; ks < 4; ++ks) {
      short8 k0 = *(const short8*)(Klds[cur] + rb0 + ((ks * 32 + hl16) ^ sw0));
      short8 k1 = *(const short8*)(Klds[cur] + rb1 + ((ks * 32 + hl16) ^ sw0));
      s0 = mfma32(k0, qf[ks], s0);
      s1 = mfma32(k1, qf[ks], s1);
    }
    __builtin_amdgcn_s_setprio(0);

    // ---- online softmax (log2 domain; lane owns q-col, 32 local scores) ----
    float g0 = fmaxf(fmaxf(s0[0], s0[1]), fmaxf(s0[2], s0[3]));
    float g1 = fmaxf(fmaxf(s0[4], s0[5]), fmaxf(s0[6], s0[7]));
    float g2 = fmaxf(fmaxf(s0[8], s0[9]), fmaxf(s0[10], s0[11]));
    float g3 = fmaxf(fmaxf(s0[12], s0[13]), fmaxf(s0[14], s0[15]));
    float g4 = fmaxf(fmaxf(s1[0], s1[1]), fmaxf(s1[2], s1[3]));
    float g5 = fmaxf(fmaxf(s1[4], s1[5]), fmaxf(s1[6], s1[7]));
    float g6 = fmaxf(fmaxf(s1[8], s1[9]), fmaxf(s1[10], s1[11]));
    float g7 = fmaxf(fmaxf(s1[12], s1[13]), fmaxf(s1[14], s1[15]));
    float mloc = fmaxf(fmaxf(fmaxf(g0, g1), fmaxf(g2, g3)),
                       fmaxf(fmaxf(g4, g5), fmaxf(g6, g7)));
    float tmax = fmaxf(mloc, __shfl_xor(mloc, 32));
    if (!__all(tmax <= mrun + 8.f)) {
      float mnew = fmaxf(mrun, tmax);
      float alpha = __builtin_exp2f(mrun - mnew);
      mrun = mnew;
#pragma unroll
      for (int i = 0; i < 16; ++i) {
        o0[i] *= alpha; o1[i] *= alpha; lacc[i] *= alpha;
      }
    }
    unsigned c0[8], c1[8];
#pragma unroll
    for (int i = 0; i < 8; ++i)
      c0[i] = cvtpk(__builtin_exp2f(s0[2 * i] - mrun),
                    __builtin_exp2f(s0[2 * i + 1] - mrun));
#pragma unroll
    for (int i = 0; i < 8; ++i)
      c1[i] = cvtpk(__builtin_exp2f(s1[2 * i] - mrun),
                    __builtin_exp2f(s1[2 * i + 1] - mrun));

    // ---- redistribute P into PV B-fragments (permlane32_swap) ----
    {
      u32x2 r;
      r = __builtin_amdgcn_permlane32_swap(c0[0], c0[2], false, false); c0[0] = r[0]; c0[2] = r[1];
      r = __builtin_amdgcn_permlane32_swap(c0[1], c0[3], false, false); c0[1] = r[0]; c0[3] = r[1];
      r = __builtin_amdgcn_permlane32_swap(c0[4], c0[6], false, false); c0[4] = r[0]; c0[6] = r[1];
      r = __builtin_amdgcn_permlane32_swap(c0[5], c0[7], false, false); c0[5] = r[0]; c0[7] = r[1];
      r = __builtin_amdgcn_permlane32_swap(c1[0], c1[2], false, false); c1[0] = r[0]; c1[2] = r[1];
      r = __builtin_amdgcn_permlane32_swap(c1[1], c1[3], false, false); c1[1] = r[0]; c1[3] = r[1];
      r = __builtin_amdgcn_permlane32_swap(c1[4], c1[6], false, false); c1[4] = r[0]; c1[6] = r[1];
      r = __builtin_amdgcn_permlane32_swap(c1[5], c1[7], false, false); c1[5] = r[0]; c1[7] = r[1];
    }
    short8 pf[4];
    {
      union { unsigned u[4]; short8 s; } t;
      t.u[0] = c0[0]; t.u[1] = c0[1]; t.u[2] = c0[2]; t.u[3] = c0[3]; pf[0] = t.s;
      t.u[0] = c0[4]; t.u[1] = c0[5]; t.u[2] = c0[6]; t.u[3] = c0[7]; pf[1] = t.s;
      t.u[0] = c1[0]; t.u[1] = c1[1]; t.u[2] = c1[2]; t.u[3] = c1[3]; pf[2] = t.s;
      t.u[0] = c1[4]; t.u[1] = c1[5]; t.u[2] = c1[6]; t.u[3] = c1[7]; pf[3] = t.s;
    }

    // ---- PV: O[d][q] += Vt[d][s] * P[s][q]; l row-sum via ones-MFMA ----
    __builtin_amdgcn_s_setprio(1);
#pragma unroll
    for (int ks = 0; ks < 4; ++ks) {
      o0 = mfma32(__builtin_bit_cast(short8, vv0[ks]), pf[ks], o0);
      o1 = mfma32(__builtin_bit_cast(short8, vv1[ks]), pf[ks], o1);
      lacc = mfma32(ones, pf[ks], lacc);
    }
    __builtin_amdgcn_s_setprio(0);

    // ---- write next K tile to back buffer ----
    if (st < 31) {
      *(uint4*)(Klds[cur ^ 1] + wb0) = gk0;
      *(uint4*)(Klds[cur ^ 1] + wb1) = gk1;
    }
    __syncthreads();
    cur ^= 1;
  }

  // ---- finalize: lane holds col q, rows d; l = lacc[0] (all rows equal) ----
  float inv = 1.f / lacc[0];
#pragma unroll
  for (int dblk = 0; dblk < 2; ++dblk) {
    const f32x16& oo = dblk ? o1 : o0;
#pragma unroll
    for (int rg = 0; rg < 4; ++rg) {
      int d0 = dblk * 32 + rg * 8 + hl * 4;
      uint2 w;
      w.x = cvtpk(oo[rg * 4 + 0] * inv, oo[rg * 4 + 1] * inv);
      w.y = cvtpk(oo[rg * 4 + 2] * inv, oo[rg * 4 + 3] * inv);
      *(uint2*)(Og + ((size_t)b * 2048 + q) * 512 + h * 64 + d0) = w;
    }
  }
}

// ---------------------------------------------------------------------------
extern "C" void kernel_launch(void* const* d_in, const int* in_sizes, int n_in,
                              void* d_out, int out_size, void* d_ws, size_t ws_size,
                              hipStream_t stream) {
  (void)in_sizes; (void)n_in; (void)out_size; (void)ws_size;
  const float* query = (const float*)d_in[0];
  const float* key   = (const float*)d_in[1];
  const float* value = (const float*)d_in[2];
  const float* Wq    = (const float*)d_in[3];
  const float* Wk    = (const float*)d_in[4];
  const float* Wv    = (const float*)d_in[5];
  const float* Wo    = (const float*)d_in[6];

  const size_t TOK = (size_t)NB * NL * MODEL;
  unsigned short* Qw = (unsigned short*)d_ws;
  unsigned short* Kw = Qw + TOK;
  unsigned short* Vw = Kw + TOK;   // transposed [b][h*64+d][s]
  unsigned short* Aw = Vw + TOK;   // attended [b][l][512]

  qkv512<<<768, 256, 0, stream>>>(query, key, value, Wq, Wk, Wv, Qw, Kw, Vw);
  attn32<<<512, 256, 0, stream>>>(Qw, Kw, Vw, Aw);
  gemmWo<<<512, 256, 0, stream>>>(Aw, Wo, (float*)d_out);
}

// Round 5
// 132.179 us; speedup vs baseline: 1.1618x; 1.1618x over previous
//
#include <hip/hip_runtime.h>
#include <stdint.h>
#include <stddef.h>

#define NB 4
#define NL 2048
#define MODEL 512
#define NH 8
#define HD 64

// Q pre-scale: (1/sqrt(64)) * log2(e) -> scores in log2 domain
#define QSCALE 0.18033688011112042f

typedef __attribute__((ext_vector_type(8))) short short8;
typedef __attribute__((ext_vector_type(8))) __bf16 bf16x8;
typedef __attribute__((ext_vector_type(4))) float f32x4;
typedef __attribute__((ext_vector_type(16))) float f32x16;
typedef __attribute__((ext_vector_type(2))) unsigned int u32x2;

// round-to-nearest-even fp32 -> bf16 (bit pattern)
static __device__ __forceinline__ unsigned short f2bf(float x) {
  union { float f; unsigned u; } v; v.f = x;
  unsigned r = v.u + 0x7FFFu + ((v.u >> 16) & 1u);
  return (unsigned short)(r >> 16);
}

// packed fp32x2 -> bf16x2 (single HW instruction)
static __device__ __forceinline__ unsigned cvtpk(float lo, float hi) {
  unsigned r;
  asm("v_cvt_pk_bf16_f32 %0, %1, %2" : "=v"(r) : "v"(lo), "v"(hi));
  return r;
}

static __device__ __forceinline__ f32x4 mfma16(short8 a, short8 b, f32x4 c) {
  return __builtin_amdgcn_mfma_f32_16x16x32_bf16(
      __builtin_bit_cast(bf16x8, a), __builtin_bit_cast(bf16x8, b), c, 0, 0, 0);
}

static __device__ __forceinline__ f32x16 mfma32(short8 a, short8 b, f32x16 c) {
  return __builtin_amdgcn_mfma_f32_32x32x16_bf16(
      __builtin_bit_cast(bf16x8, a), __builtin_bit_cast(bf16x8, b), c, 0, 0, 0);
}

#define GLOAD_LDS(gp, lp)                                                      \
  __builtin_amdgcn_global_load_lds(                                            \
      (const __attribute__((address_space(1))) void*)(gp),                     \
      (__attribute__((address_space(3))) void*)(lp), 16, 0, 0)

// ---------------------------------------------------------------------------
// Merged Q/K/V projection: grid 768 = 3 x 256, 256 thr (4 waves 2x2).
// C[m][n] = A[m][k] * W[n][k]; which 0: Q bf16 (scaled), 1: K bf16,
// 2: V transposed Vt[b][n][s].
// ---------------------------------------------------------------------------
__global__ __launch_bounds__(256) void qkv512(const float* __restrict__ Aq,
                                              const float* __restrict__ Ak,
                                              const float* __restrict__ Av,
                                              const float* __restrict__ Wqp,
                                              const float* __restrict__ Wkp,
                                              const float* __restrict__ Wvp,
                                              unsigned short* __restrict__ Qo,
                                              unsigned short* __restrict__ Ko,
                                              unsigned short* __restrict__ Vto) {
  __shared__ unsigned short Alds[128][72];
  __shared__ unsigned short Wlds[128][72];

  const int which = blockIdx.x >> 8;
  const int bid = blockIdx.x & 255;
  const float* A = which == 0 ? Aq : which == 1 ? Ak : Av;
  const float* W = which == 0 ? Wqp : which == 1 ? Wkp : Wvp;

  const int tid = threadIdx.x;
  const int bn = bid & 3;
  const int bm = bid >> 2;
  const int mbase = bm * 128, nbase = bn * 128;
  const int wid = tid >> 6, lane = tid & 63;
  const int lo = lane & 15, grp = lane >> 4;
  const int wm = wid >> 1, wn = wid & 1;

  f32x4 acc[4][4] = {};

#pragma unroll 1
  for (int kb = 0; kb < 8; ++kb) {
#pragma unroll
    for (int it = 0; it < 8; ++it) {
      int id = tid + it * 256;
      int row = id >> 4, cg = id & 15;
      float4 v = *(const float4*)(A + (size_t)(mbase + row) * 512 + kb * 64 + cg * 4);
      uint2 w; w.x = cvtpk(v.x, v.y); w.y = cvtpk(v.z, v.w);
      *(uint2*)&Alds[row][cg * 4] = w;
    }
#pragma unroll
    for (int it = 0; it < 8; ++it) {
      int id = tid + it * 256;
      int row = id >> 4, cg = id & 15;
      float4 v = *(const float4*)(W + (size_t)(nbase + row) * 512 + kb * 64 + cg * 4);
      uint2 w; w.x = cvtpk(v.x, v.y); w.y = cvtpk(v.z, v.w);
      *(uint2*)&Wlds[row][cg * 4] = w;
    }
    __syncthreads();

#pragma unroll
    for (int kk = 0; kk < 2; ++kk) {
      short8 aw[4], ba[4];
#pragma unroll
      for (int f = 0; f < 4; ++f)
        aw[f] = *(const short8*)&Wlds[wn * 64 + f * 16 + lo][kk * 32 + grp * 8];
#pragma unroll
      for (int f = 0; f < 4; ++f)
        ba[f] = *(const short8*)&Alds[wm * 64 + f * 16 + lo][kk * 32 + grp * 8];
#pragma unroll
      for (int mf = 0; mf < 4; ++mf)
#pragma unroll
        for (int nf = 0; nf < 4; ++nf)
          acc[mf][nf] = mfma16(aw[nf], ba[mf], acc[mf][nf]);
    }
    __syncthreads();
  }

  const float scale = (which == 0) ? QSCALE : 1.0f;
#pragma unroll
  for (int mf = 0; mf < 4; ++mf)
#pragma unroll
    for (int nf = 0; nf < 4; ++nf) {
      int m = mbase + wm * 64 + mf * 16 + lo;
      int n0 = nbase + wn * 64 + nf * 16 + grp * 4;
      f32x4 a = acc[mf][nf];
      if (which < 2) {
        unsigned short* C = which == 0 ? Qo : Ko;
        uint2 w;
        w.x = cvtpk(a[0] * scale, a[1] * scale);
        w.y = cvtpk(a[2] * scale, a[3] * scale);
        *(uint2*)(C + (size_t)m * 512 + n0) = w;
      } else {
        int b = m >> 11, s = m & 2047;
#pragma unroll
        for (int i = 0; i < 4; ++i)
          Vto[((size_t)b * 512 + n0 + i) * 2048 + s] = f2bf(a[i]);
      }
    }
}

// ---------------------------------------------------------------------------
// Output projection (bf16 A, fp32 out). 128x128 tiles, grid 256.
// ---------------------------------------------------------------------------
__global__ __launch_bounds__(256) void gemmWo(const unsigned short* __restrict__ A,
                                              const float* __restrict__ W,
                                              float* __restrict__ C) {
  __shared__ unsigned short Alds[128][72];
  __shared__ unsigned short Wlds[128][72];

  const int tid = threadIdx.x;
  const int bn = blockIdx.x & 3;
  const int bm = blockIdx.x >> 2;
  const int mbase = bm * 128, nbase = bn * 128;
  const int wid = tid >> 6, lane = tid & 63;
  const int lo = lane & 15, grp = lane >> 4;
  const int wm = wid >> 1, wn = wid & 1;

  f32x4 acc[4][4] = {};

#pragma unroll 1
  for (int kb = 0; kb < 8; ++kb) {
#pragma unroll
    for (int it = 0; it < 4; ++it) {
      int id = tid + it * 256;
      int row = id >> 3, cg = id & 7;
      uint4 v = *(const uint4*)(A + (size_t)(mbase + row) * 512 + kb * 64 + cg * 8);
      *(uint4*)&Alds[row][cg * 8] = v;
    }
#pragma unroll
    for (int it = 0; it < 8; ++it) {
      int id = tid + it * 256;
      int row = id >> 4, cg = id & 15;
      float4 v = *(const float4*)(W + (size_t)(nbase + row) * 512 + kb * 64 + cg * 4);
      uint2 w; w.x = cvtpk(v.x, v.y); w.y = cvtpk(v.z, v.w);
      *(uint2*)&Wlds[row][cg * 4] = w;
    }
    __syncthreads();

#pragma unroll
    for (int kk = 0; kk < 2; ++kk) {
      short8 aw[4], ba[4];
#pragma unroll
      for (int f = 0; f < 4; ++f)
        aw[f] = *(const short8*)&Wlds[wn * 64 + f * 16 + lo][kk * 32 + grp * 8];
#pragma unroll
      for (int f = 0; f < 4; ++f)
        ba[f] = *(const short8*)&Alds[wm * 64 + f * 16 + lo][kk * 32 + grp * 8];
#pragma unroll
      for (int mf = 0; mf < 4; ++mf)
#pragma unroll
        for (int nf = 0; nf < 4; ++nf)
          acc[mf][nf] = mfma16(aw[nf], ba[mf], acc[mf][nf]);
    }
    __syncthreads();
  }

#pragma unroll
  for (int mf = 0; mf < 4; ++mf)
#pragma unroll
    for (int nf = 0; nf < 4; ++nf) {
      int m = mbase + wm * 64 + mf * 16 + lo;
      int n0 = nbase + wn * 64 + nf * 16 + grp * 4;
      f32x4 a = acc[mf][nf];
      float4 o;
      o.x = a[0]; o.y = a[1]; o.z = a[2]; o.w = a[3];
      *(float4*)(C + (size_t)m * 512 + n0) = o;
    }
}

// ---------------------------------------------------------------------------
// Flash attention v5: 32x32x16 MFMA, in-register P (cvt_pk + permlane),
// K AND V staged in LDS via global_load_lds DMA (pre-swizzled source,
// XOR-swizzled b128 reads), double-buffered; l via ones-MFMA; defer-max;
// XCD chunk swizzle. 4 waves x 32 q = 128 q/block; grid 512.
// ---------------------------------------------------------------------------
__global__ __launch_bounds__(256, 2) void attn32(const unsigned short* __restrict__ Qg,
                                                 const unsigned short* __restrict__ Kg,
                                                 const unsigned short* __restrict__ Vt,
                                                 unsigned short* __restrict__ Og) {
  __shared__ char Klds[2][8192];   // [buf][64 rows x 128B], XOR-swizzled
  __shared__ char Vlds[2][8192];   // [buf][64 d-rows x 128B], XOR-swizzled

  const int tid = threadIdx.x;
  const int wid = tid >> 6, lane = tid & 63;
  const int ln31 = lane & 31, hl = lane >> 5;

  // XCD chunk swizzle: XCD x gets logical blocks [x*64, x*64+64) = 4 bh groups
  const int lb = ((blockIdx.x & 7) << 6) + (blockIdx.x >> 3);
  const int bh = lb >> 4, qb = lb & 15;
  const int b = bh >> 3, h = bh & 7;

  const unsigned short* Kbh = Kg + (size_t)b * 2048 * 512 + h * 64;
  const unsigned short* Vbh = Vt + ((size_t)b * 512 + h * 64) * 2048;
  const int q = qb * 128 + wid * 32 + ln31;     // this lane's q-column

  // Q B-fragments: col=q, k(d) = ks*16 + hl*8 + j
  short8 qf[4];
#pragma unroll
  for (int ks = 0; ks < 4; ++ks)
    qf[ks] = *(const short8*)(Qg + ((size_t)b * 2048 + q) * 512 + h * 64 + ks * 16 + hl * 8);

  // DMA staging: each wave stages 16 rows of K and 16 rows of V (2 instrs ea).
  // LDS is linear in lane order; global source pre-swizzled so that
  // LDS[row][slot] = G[row][slot ^ (row&7)]  (16B slots).
  const int srow = lane >> 3;                   // 0..7 within the 8-row group
  const int schunk = (lane & 7) ^ srow;         // pre-swizzled 16B chunk
  const unsigned short* kg0 = Kbh + (size_t)(wid * 16 + srow) * 512 + schunk * 8;
  const unsigned short* kg1 = kg0 + (size_t)8 * 512;
  const unsigned short* vg0 = Vbh + (size_t)(wid * 16 + srow) * 2048 + schunk * 8;
  const unsigned short* vg1 = vg0 + (size_t)8 * 2048;
  const int ldso = wid * 2048;                  // wave's LDS byte base (16 rows)

  // swizzled b128 read addressing: row r, chunk c -> r*128 + (c*16 ^ ((r&7)<<4))
  const int rb0 = ln31 * 128, rb1 = rb0 + 32 * 128;
  const int sw = (ln31 & 7) << 4;
  const int hl16 = hl * 16;

  float mrun = -1e30f;
  f32x16 o0 = {}, o1 = {}, lacc = {};
  const short8 ones = {0x3F80, 0x3F80, 0x3F80, 0x3F80, 0x3F80, 0x3F80, 0x3F80, 0x3F80};

  // prologue: stage tile 0
  GLOAD_LDS(kg0, Klds[0] + ldso);
  GLOAD_LDS(kg1, Klds[0] + ldso + 1024);
  GLOAD_LDS(vg0, Vlds[0] + ldso);
  GLOAD_LDS(vg1, Vlds[0] + ldso + 1024);
  __syncthreads();

  int cur = 0;
#pragma unroll 1
  for (int st = 0; st < 32; ++st) {
    // prefetch next tile into back buffer (in flight through this tile's compute)
    if (st < 31) {
      size_t ko = (size_t)(st + 1) * 64 * 512;
      size_t vo = (size_t)(st + 1) * 64;
      GLOAD_LDS(kg0 + ko, Klds[cur ^ 1] + ldso);
      GLOAD_LDS(kg1 + ko, Klds[cur ^ 1] + ldso + 1024);
      GLOAD_LDS(vg0 + vo, Vlds[cur ^ 1] + ldso);
      GLOAD_LDS(vg1 + vo, Vlds[cur ^ 1] + ldso + 1024);
    }

    // ---- QK^T: D[s][q], two 32-row s-blocks ----
    f32x16 s0 = {}, s1 = {};
    __builtin_amdgcn_s_setprio(1);
#pragma unroll
    for (int ks = 0; ks < 4; ++ks) {
      short8 k0 = *(const short8*)(Klds[cur] + rb0 + ((ks * 32 + hl16) ^ sw));
      short8 k1 = *(const short8*)(Klds[cur] + rb1 + ((ks * 32 + hl16) ^ sw));
      s0 = mfma32(k0, qf[ks], s0);
      s1 = mfma32(k1, qf[ks], s1);
    }
    __builtin_amdgcn_s_setprio(0);

    // ---- online softmax (log2 domain; lane owns q-col, 32 local scores) ----
    float g0 = fmaxf(fmaxf(s0[0], s0[1]), fmaxf(s0[2], s0[3]));
    float g1 = fmaxf(fmaxf(s0[4], s0[5]), fmaxf(s0[6], s0[7]));
    float g2 = fmaxf(fmaxf(s0[8], s0[9]), fmaxf(s0[10], s0[11]));
    float g3 = fmaxf(fmaxf(s0[12], s0[13]), fmaxf(s0[14], s0[15]));
    float g4 = fmaxf(fmaxf(s1[0], s1[1]), fmaxf(s1[2], s1[3]));
    float g5 = fmaxf(fmaxf(s1[4], s1[5]), fmaxf(s1[6], s1[7]));
    float g6 = fmaxf(fmaxf(s1[8], s1[9]), fmaxf(s1[10], s1[11]));
    float g7 = fmaxf(fmaxf(s1[12], s1[13]), fmaxf(s1[14], s1[15]));
    float mloc = fmaxf(fmaxf(fmaxf(g0, g1), fmaxf(g2, g3)),
                       fmaxf(fmaxf(g4, g5), fmaxf(g6, g7)));
    float tmax = fmaxf(mloc, __shfl_xor(mloc, 32));
    if (!__all(tmax <= mrun + 8.f)) {
      float mnew = fmaxf(mrun, tmax);
      float alpha = __builtin_exp2f(mrun - mnew);
      mrun = mnew;
      lacc[0] *= alpha;                     // only [0] is consumed
#pragma unroll
      for (int i = 0; i < 16; ++i) { o0[i] *= alpha; o1[i] *= alpha; }
    }
    unsigned c0[8], c1[8];
#pragma unroll
    for (int i = 0; i < 8; ++i)
      c0[i] = cvtpk(__builtin_exp2f(s0[2 * i] - mrun),
                    __builtin_exp2f(s0[2 * i + 1] - mrun));
#pragma unroll
    for (int i = 0; i < 8; ++i)
      c1[i] = cvtpk(__builtin_exp2f(s1[2 * i] - mrun),
                    __builtin_exp2f(s1[2 * i + 1] - mrun));

    // ---- redistribute P into PV B-fragments (permlane32_swap) ----
    {
      u32x2 r;
      r = __builtin_amdgcn_permlane32_swap(c0[0], c0[2], false, false); c0[0] = r[0]; c0[2] = r[1];
      r = __builtin_amdgcn_permlane32_swap(c0[1], c0[3], false, false); c0[1] = r[0]; c0[3] = r[1];
      r = __builtin_amdgcn_permlane32_swap(c0[4], c0[6], false, false); c0[4] = r[0]; c0[6] = r[1];
      r = __builtin_amdgcn_permlane32_swap(c0[5], c0[7], false, false); c0[5] = r[0]; c0[7] = r[1];
      r = __builtin_amdgcn_permlane32_swap(c1[0], c1[2], false, false); c1[0] = r[0]; c1[2] = r[1];
      r = __builtin_amdgcn_permlane32_swap(c1[1], c1[3], false, false); c1[1] = r[0]; c1[3] = r[1];
      r = __builtin_amdgcn_permlane32_swap(c1[4], c1[6], false, false); c1[4] = r[0]; c1[6] = r[1];
      r = __builtin_amdgcn_permlane32_swap(c1[5], c1[7], false, false); c1[5] = r[0]; c1[7] = r[1];
    }
    short8 pf[4];
    {
      union { unsigned u[4]; short8 s; } t;
      t.u[0] = c0[0]; t.u[1] = c0[1]; t.u[2] = c0[2]; t.u[3] = c0[3]; pf[0] = t.s;
      t.u[0] = c0[4]; t.u[1] = c0[5]; t.u[2] = c0[6]; t.u[3] = c0[7]; pf[1] = t.s;
      t.u[0] = c1[0]; t.u[1] = c1[1]; t.u[2] = c1[2]; t.u[3] = c1[3]; pf[2] = t.s;
      t.u[0] = c1[4]; t.u[1] = c1[5]; t.u[2] = c1[6]; t.u[3] = c1[7]; pf[3] = t.s;
    }

    // ---- PV: O[d][q] += Vt[d][s] * P[s][q]; l row-sum via ones-MFMA ----
    __builtin_amdgcn_s_setprio(1);
#pragma unroll
    for (int ks = 0; ks < 4; ++ks) {
      short8 v0 = *(const short8*)(Vlds[cur] + rb0 + ((ks * 32 + hl16) ^ sw));
      short8 v1 = *(const short8*)(Vlds[cur] + rb1 + ((ks * 32 + hl16) ^ sw));
      o0 = mfma32(v0, pf[ks], o0);
      o1 = mfma32(v1, pf[ks], o1);
      lacc = mfma32(ones, pf[ks], lacc);
    }
    __builtin_amdgcn_s_setprio(0);

    __syncthreads();   // drains DMA prefetch + orders LDS reuse
    cur ^= 1;
  }

  // ---- finalize: lane holds col q, rows d; l = lacc[0] ----
  float inv = 1.f / lacc[0];
#pragma unroll
  for (int dblk = 0; dblk < 2; ++dblk) {
    const f32x16& oo = dblk ? o1 : o0;
#pragma unroll
    for (int rg = 0; rg < 4; ++rg) {
      int d0 = dblk * 32 + rg * 8 + hl * 4;
      uint2 w;
      w.x = cvtpk(oo[rg * 4 + 0] * inv, oo[rg * 4 + 1] * inv);
      w.y = cvtpk(oo[rg * 4 + 2] * inv, oo[rg * 4 + 3] * inv);
      *(uint2*)(Og + ((size_t)b * 2048 + q) * 512 + h * 64 + d0) = w;
    }
  }
}

// ---------------------------------------------------------------------------
extern "C" void kernel_launch(void* const* d_in, const int* in_sizes, int n_in,
                              void* d_out, int out_size, void* d_ws, size_t ws_size,
                              hipStream_t stream) {
  (void)in_sizes; (void)n_in; (void)out_size; (void)ws_size;
  const float* query = (const float*)d_in[0];
  const float* key   = (const float*)d_in[1];
  const float* value = (const float*)d_in[2];
  const float* Wq    = (const float*)d_in[3];
  const float* Wk    = (const float*)d_in[4];
  const float* Wv    = (const float*)d_in[5];
  const float* Wo    = (const float*)d_in[6];

  const size_t TOK = (size_t)NB * NL * MODEL;
  unsigned short* Qw = (unsigned short*)d_ws;
  unsigned short* Kw = Qw + TOK;
  unsigned short* Vw = Kw + TOK;   // transposed [b][h*64+d][s]
  unsigned short* Aw = Vw + TOK;   // attended [b][l][512]

  qkv512<<<768, 256, 0, stream>>>(query, key, value, Wq, Wk, Wv, Qw, Kw, Vw);
  attn32<<<512, 256, 0, stream>>>(Qw, Kw, Vw, Aw);
  gemmWo<<<256, 256, 0, stream>>>(Aw, Wo, (float*)d_out);
}